// Round 9
// baseline (1468.805 us; speedup 1.0000x reference)
//
#include <hip/hip_runtime.h>
#include <math.h>

#define HH 128
#define NPIX 16384
#define BB 8
#define MM 4096
#define NN 16384
#define LRELU_S 0.1f

typedef __attribute__((ext_vector_type(8))) short bf16x8;
typedef __attribute__((ext_vector_type(4))) float f32x4;

__device__ __forceinline__ float leaky_(float v){ return v >= 0.f ? v : LRELU_S*v; }
__device__ __forceinline__ float clamp01(float v){ return fminf(fmaxf(v, 0.f), 1.f); }
__device__ __forceinline__ float clamp02(float v){ return fminf(fmaxf(v, 0.f), 2.f); }
__device__ __forceinline__ unsigned short f2bf(float f){
  unsigned u = __float_as_uint(f);
  u = (u + 0x7FFFu + ((u >> 16) & 1u)) >> 16;
  return (unsigned short)u;
}
__device__ __forceinline__ float bf2f(unsigned short s){
  return __uint_as_float(((unsigned)s) << 16);
}

// ---------- prep: A f32 -> Abf bf16 (row-major) ----------
__global__ __launch_bounds__(256) void k_prep(const float* __restrict__ A_,
                                              unsigned short* __restrict__ Abf){
  size_t i = ((size_t)blockIdx.x*256 + threadIdx.x)*8;
  float4 v0 = *(const float4*)&A_[i];
  float4 v1 = *(const float4*)&A_[i+4];
  unsigned short o[8] = { f2bf(v0.x), f2bf(v0.y), f2bf(v0.z), f2bf(v0.w),
                          f2bf(v1.x), f2bf(v1.y), f2bf(v1.z), f2bf(v1.w) };
  *(uint4*)&Abf[i] = *(uint4*)o;
}

// ---------- prep2: pack Abf -> Apk[mt][k8][col][8] (MFMA-fragment order) ----------
// Apk[((mt*2048 + k8)*16 + col)*8 + e] = Abf[(mt*16+col)*NN + k8*8 + e]
__global__ __launch_bounds__(256) void k_prep2(const unsigned short* __restrict__ Abf,
                                               unsigned short* __restrict__ Apk){
  size_t c = (size_t)blockIdx.x*256 + threadIdx.x;   // 8M chunks of 16 B
  int col = (int)(c & 15);
  int k8  = (int)((c >> 4) & 2047);
  int mt  = (int)(c >> 15);
  uint4 v = *(const uint4*)&Abf[(size_t)(mt*16 + col)*NN + k8*8];
  *(uint4*)&Apk[c*8] = v;
}

// ---------- dn[b] = ||d[b,:]|| ----------
__global__ __launch_bounds__(256) void k_dn(const float* __restrict__ d, float* __restrict__ dn){
  int b = blockIdx.x, t = threadIdx.x;
  float ss = 0.f;
  for (int m=t; m<MM; m+=256){ float v = d[b*MM + m]; ss += v*v; }
  #pragma unroll
  for (int off=32; off; off>>=1) ss += __shfl_down(ss, off);
  __shared__ float red[4];
  if ((t & 63) == 0) red[t>>6] = ss;
  __syncthreads();
  if (t == 0) dn[b] = sqrtf(red[0]+red[1]+red[2]+red[3]);
}

// ---------- K_A: gemm1 partials (packed-A). 1024 blocks (mt x ng), 256 thr ----------
// R8-proven math; A addressing remapped to pack:
// k = ng*4096 + w*1024 + s*32 + kg*8 + e  ->  k8 = ng*512 + w*128 + s*4 + kg
// addr = ((mt*2048 + k8)*16 + col)*8 ; step s: +512 shorts (wave-load = 1024 B contiguous)
__global__ __launch_bounds__(256) void k_gemm1p(const unsigned short* __restrict__ Apk,
    const unsigned short* __restrict__ xtt, float* __restrict__ e_part){
  __shared__ float part[4][16][16];
  int blk = blockIdx.x;
  int mt = blk >> 2, ng = blk & 3;
  int t = threadIdx.x, w = t >> 6, lane = t & 63;
  int kg = lane >> 4, col = lane & 15;
  const unsigned short* Ap = Apk + (((size_t)mt*2048 + ng*512 + w*128 + kg)*16 + col)*8;
  const unsigned short* Bp = xtt + ((size_t)(ng*512 + w*128 + kg)*16 + col)*8;
  f32x4 acc = {0.f,0.f,0.f,0.f};
  #pragma unroll 8
  for (int s=0; s<32; ++s){
    bf16x8 a = *(const bf16x8*)(Ap + s*512);
    bf16x8 b = *(const bf16x8*)(Bp + s*512);
    acc = __builtin_amdgcn_mfma_f32_16x16x32_bf16(a, b, acc, 0, 0, 0);
  }
  #pragma unroll
  for (int j=0;j<4;++j) part[w][kg*4+j][col] = acc[j];
  __syncthreads();
  int r = t >> 4, b = t & 15;
  float s = part[0][r][b] + part[1][r][b] + part[2][r][b] + part[3][r][b];
  e_part[((size_t)ng*MM + mt*16 + r)*16 + b] = s;
}

// ---------- K_B: heterogeneous. blocks 0..511 gemm2 u-partials; 512..639 conv chain ----------
__global__ __launch_bounds__(256) void k_phaseB(const unsigned short* __restrict__ Abf,
    const float* __restrict__ e_part, const float* __restrict__ d_,
    const float* __restrict__ x,
    const float* __restrict__ wK, const float* __restrict__ w1, const float* __restrict__ b1,
    const float* __restrict__ w2, const float* __restrict__ b2,
    const float* __restrict__ w3, const float* __restrict__ b3,
    const float* __restrict__ alpha,
    float* __restrict__ up, float* __restrict__ d2p, float* __restrict__ rk1){
  __shared__ float smem[13312];
  __shared__ float wKs[18], w1s[100], w2s[100], w3s[100], bs[6], red8s[64];
  int blk = blockIdx.x, t = threadIdx.x;

  if (blk < 512){
    float (*zs)[128] = (float(*)[128])smem;
    int ms = blk >> 4, nb = blk & 15;
    int m0 = ms*128, n0 = nb*1024;
    for (int i=t; i<1024; i+=256){
      int ml = i >> 3, b = i & 7;
      int m = m0 + ml;
      float s = e_part[(size_t)(0*MM + m)*16 + b]
              + e_part[(size_t)(1*MM + m)*16 + b]
              + e_part[(size_t)(2*MM + m)*16 + b]
              + e_part[(size_t)(3*MM + m)*16 + b];
      zs[b][ml] = s - d_[b*MM + m];
    }
    __syncthreads();
    if (nb == 0){
      if (t < 64){
        int b = t & 7, g = t >> 3;
        float s = 0.f;
        #pragma unroll
        for (int i=0;i<16;++i){ float v = zs[b][g*16+i]; s += v*v; }
        red8s[g*8 + b] = s;
      }
      __syncthreads();
      if (t < 8){
        float s2 = 0.f;
        #pragma unroll
        for (int g=0;g<8;++g) s2 += red8s[g*8 + t];
        d2p[ms*8 + t] = s2;
      }
    }
    int h = t >> 7, cth = t & 127;
    const unsigned short* Ap = Abf + (size_t)(m0 + h*64)*NN + n0 + cth*8;
    float acc[8][8];
    #pragma unroll
    for (int c=0;c<8;++c)
      #pragma unroll
      for (int b=0;b<8;++b) acc[c][b] = 0.f;
    for (int mo=0; mo<64; mo+=8){
      uint4 a8[8];
      #pragma unroll
      for (int u=0;u<8;++u) a8[u] = *(const uint4*)(Ap + (size_t)(mo+u)*NN);
      #pragma unroll
      for (int u=0;u<8;++u){
        float av[8];
        av[0]=bf2f((unsigned short)(a8[u].x & 0xffff)); av[1]=bf2f((unsigned short)(a8[u].x >> 16));
        av[2]=bf2f((unsigned short)(a8[u].y & 0xffff)); av[3]=bf2f((unsigned short)(a8[u].y >> 16));
        av[4]=bf2f((unsigned short)(a8[u].z & 0xffff)); av[5]=bf2f((unsigned short)(a8[u].z >> 16));
        av[6]=bf2f((unsigned short)(a8[u].w & 0xffff)); av[7]=bf2f((unsigned short)(a8[u].w >> 16));
        int ml = h*64 + mo + u;
        #pragma unroll
        for (int b=0;b<8;++b){
          float z = zs[b][ml];
          #pragma unroll
          for (int c=0;c<8;++c) acc[c][b] += av[c]*z;
        }
      }
    }
    int pg = ms*2 + h;
    #pragma unroll
    for (int b=0;b<8;++b){
      float4 v0 = {acc[0][b], acc[1][b], acc[2][b], acc[3][b]};
      float4 v1 = {acc[4][b], acc[5][b], acc[6][b], acc[7][b]};
      float* dst = &up[((size_t)pg*8 + b)*NN + n0 + cth*8];
      *(float4*)dst = v0;
      *(float4*)(dst+4) = v1;
    }
    return;
  }

  // ===== conv role (proven) =====
  int cb = blk - 512;
  int b = cb >> 4, slab = cb & 15, r0 = slab*8;
  float (*xs)[128] = (float(*)[128])&smem[0];
  float (*bufA)[22][128] = (float(*)[22][128])&smem[3072];
  float (*bufB)[18][128] = (float(*)[18][128])&smem[8704];
  float twoa = 2.f*clamp02(alpha[0]);
  for (int i=t;i<18;i+=256) wKs[i]=wK[i];
  for (int i=t;i<100;i+=256){ w1s[i]=w1[i]; w2s[i]=w2[i]; w3s[i]=w3[i]; }
  if (t<2){ bs[t]=b1[t]; bs[2+t]=b2[t]; bs[4+t]=b3[t]; }
  for (int idx=t; idx<24*128; idx+=256){
    int i = idx>>7, j = idx&127, ir = r0-8+i;
    xs[i][j] = ((unsigned)ir < 128u) ? x[b*NPIX + ir*HH + j] : 0.f;
  }
  __syncthreads();
  for (int c=0;c<2;++c)
    for (int idx=t; idx<22*128; idx+=256){
      int i = idx>>7, j = idx&127, ir = r0-7+i;
      float s = 0.f;
      if ((unsigned)ir < 128u){
        #pragma unroll
        for (int di=0;di<3;++di)
          #pragma unroll
          for (int dj=0;dj<3;++dj){
            int jj = j+dj-1;
            if ((unsigned)jj < 128u) s += xs[i+di][jj]*wKs[(c*3+di)*3+dj];
          }
      }
      bufA[c][i][j] = s;
    }
  __syncthreads();
  for (int o=0;o<2;++o)
    for (int idx=t; idx<18*128; idx+=256){
      int i = idx>>7, j = idx&127, ir = r0-5+i;
      float v = 0.f;
      if ((unsigned)ir < 128u){
        float s = bs[o];
        #pragma unroll
        for (int c=0;c<2;++c)
          #pragma unroll
          for (int di=0;di<5;++di)
            #pragma unroll
            for (int dj=0;dj<5;++dj){
              int jj = j+dj-2;
              if ((unsigned)jj < 128u) s += bufA[c][i+di][jj]*w1s[(o*2+c)*25+di*5+dj];
            }
        v = bufA[o][i+2][j] + leaky_(s);
      }
      bufB[o][i][j] = v;
    }
  __syncthreads();
  for (int o=0;o<2;++o)
    for (int idx=t; idx<14*128; idx+=256){
      int i = idx>>7, j = idx&127, ir = r0-3+i;
      float v = 0.f;
      if ((unsigned)ir < 128u){
        float s = bs[2+o];
        #pragma unroll
        for (int c=0;c<2;++c)
          #pragma unroll
          for (int di=0;di<5;++di)
            #pragma unroll
            for (int dj=0;dj<5;++dj){
              int jj = j+dj-2;
              if ((unsigned)jj < 128u) s += bufB[c][i+di][jj]*w2s[(o*2+c)*25+di*5+dj];
            }
        v = bufB[o][i+2][j] + leaky_(s);
      }
      bufA[o][i][j] = v;
    }
  __syncthreads();
  for (int o=0;o<2;++o)
    for (int idx=t; idx<10*128; idx+=256){
      int i = idx>>7, j = idx&127, ir = r0-1+i;
      float v = 0.f;
      if ((unsigned)ir < 128u){
        float s = bs[4+o];
        #pragma unroll
        for (int c=0;c<2;++c)
          #pragma unroll
          for (int di=0;di<5;++di)
            #pragma unroll
            for (int dj=0;dj<5;++dj){
              int jj = j+dj-2;
              if ((unsigned)jj < 128u) s += bufA[c][i+di][jj]*w3s[(o*2+c)*25+di*5+dj];
            }
        v = bufA[o][i+2][j] + leaky_(s);
      }
      bufB[o][i][j] = v;
    }
  __syncthreads();
  for (int c=0;c<2;++c)
    for (int idx=t; idx<10*128; idx+=256){
      int i = idx>>7, j = idx&127, ir = r0-1+i;
      float v = 0.f;
      if ((unsigned)ir < 128u){
        float kx = 0.f;
        #pragma unroll
        for (int di=0;di<3;++di)
          #pragma unroll
          for (int dj=0;dj<3;++dj){
            int jj = j+dj-1;
            if ((unsigned)jj < 128u) kx += xs[i+6+di][jj]*wKs[(c*3+di)*3+dj];
          }
        v = twoa*(kx - bufB[c][i][j]);
      }
      bufA[c][i][j] = v;
    }
  __syncthreads();
  for (int idx=t; idx<8*128; idx+=256){
    int i = idx>>7, j = idx&127, ir = r0+i;
    float s = 0.f;
    #pragma unroll
    for (int c=0;c<2;++c)
      #pragma unroll
      for (int di=0;di<3;++di)
        #pragma unroll
        for (int dj=0;dj<3;++dj){
          int jj = j+dj-1;
          if ((unsigned)jj < 128u) s += bufA[c][i+di][jj]*wKs[(c*3+(2-di))*3+(2-dj)];
        }
    rk1[b*NPIX + ir*HH + j] = s;
  }
}

// ---------- K_C: cf + combine + xtt pack. 512 blocks x 256 thr ----------
__global__ __launch_bounds__(256) void k_combine3(const float* __restrict__ up,
    const float* __restrict__ rk1, const float* __restrict__ d2p,
    const float* __restrict__ dn, const float* __restrict__ delta,
    const float* __restrict__ alpha, const float* __restrict__ beta,
    float* __restrict__ x, unsigned short* __restrict__ xtt){
  __shared__ float cf_s[8];
  int t = threadIdx.x;
  if (t < 8){
    float s2 = 0.f;
    #pragma unroll
    for (int ms=0; ms<32; ++ms) s2 += d2p[ms*8 + t];
    float dist = fmaxf(sqrtf(s2), 1e-10f);
    float de = expf(delta[0]);
    float a = clamp02(alpha[0]);
    cf_s[t] = 2.f*a*(1.f - fminf(1.f, de*dn[t]/dist));
  }
  __syncthreads();
  float bta = clamp02(beta[0]);
  int o = blockIdx.x*256 + t;
  int b = o >> 14, pix = o & 16383;
  float s = 0.f;
  #pragma unroll
  for (int p=0; p<64; ++p)
    s += up[((size_t)p*8 + b)*NN + pix];
  float tot = rk1[b*NPIX + pix] + cf_s[b]*s;
  float xn = clamp01(x[b*NPIX + pix] - bta*tot);
  x[b*NPIX + pix] = xn;
  xtt[((size_t)(pix>>3)*16 + b)*8 + (pix&7)] = f2bf(xn);
}

extern "C" void kernel_launch(void* const* d_in, const int* in_sizes, int n_in,
                              void* d_out, int out_size, void* d_ws, size_t ws_size,
                              hipStream_t stream) {
  const float* d_d   = (const float*)d_in[0];
  const float* d_A   = (const float*)d_in[1];
  const float* w1    = (const float*)d_in[2];
  const float* b1    = (const float*)d_in[3];
  const float* w2    = (const float*)d_in[4];
  const float* b2    = (const float*)d_in[5];
  const float* w3    = (const float*)d_in[6];
  const float* b3    = (const float*)d_in[7];
  const float* wK    = (const float*)d_in[8];
  const float* delta = (const float*)d_in[9];
  const float* alpha = (const float*)d_in[10];
  const float* beta  = (const float*)d_in[12];

  char* p = (char*)d_ws;
  unsigned short* Abf = (unsigned short*)p; p += (size_t)MM*NN*2;      // 128 MiB
  unsigned short* Apk = (unsigned short*)p; p += (size_t)MM*NN*2;      // 128 MiB
  unsigned short* xtt = (unsigned short*)p; p += (size_t)2048*16*8*2;  // 512 KiB
  float* x      = (float*)p; p += (size_t)BB*NPIX*4;
  float* rk1    = (float*)p; p += (size_t)BB*NPIX*4;
  float* e_part = (float*)p; p += (size_t)4*MM*16*4;                   // 1 MiB
  float* up     = (float*)p; p += (size_t)64*8*NN*4;                   // 32 MiB
  float* d2p    = (float*)p; p += (size_t)32*8*4;
  float* dnb    = (float*)p; p += 64;

  k_prep<<<MM*NN/(256*8), 256, 0, stream>>>(d_A, Abf);
  k_prep2<<<MM*NN/(256*8), 256, 0, stream>>>(Abf, Apk);
  k_dn<<<BB, 256, 0, stream>>>(d_d, dnb);
  hipMemsetAsync(x, 0, (size_t)BB*NPIX*4, stream);
  hipMemsetAsync(xtt, 0, (size_t)2048*16*8*2, stream);

  for (int it=0; it<9; ++it){
    k_gemm1p<<<1024, 256, 0, stream>>>(Apk, xtt, e_part);
    k_phaseB<<<640, 256, 0, stream>>>(Abf, e_part, d_d, x,
                                      wK, w1, b1, w2, b2, w3, b3, alpha,
                                      up, d2p, rk1);
    k_combine3<<<512, 256, 0, stream>>>(up, rk1, d2p, dnb, delta, alpha, beta, x, xtt);
  }

  hipMemcpyAsync(d_out, x, (size_t)BB*NPIX*4, hipMemcpyDeviceToDevice, stream);
}